// Round 1
// 235.003 us; speedup vs baseline: 1.0149x; 1.0149x over previous
//
#include <hip/hip_runtime.h>
#include <math.h>

// Causal depthwise conv1d K=4 + SiLU. x (B=4, T=4096, C=2048) fp32, kernel (4, C) fp32.
// y[b,t,c] = silu( sum_j k[j,c] * x[b,t-j,c] ), zero-padded; next_cache = x[:, T-3:, :].
//
// R1: TT=16, batch-of-4 loads, launch_bounds(512,8).
// R3 analysis: VGPR_Count=32 (!) -> launch_bounds(512,8) starved the allocator; the
//   4-deep load batch was serialized into load;waitcnt(0);use chains. VALUBusy 18%,
//   HBM 2.6/6.3 TB/s, nothing saturated = self-inflicted latency bound.
// R3 fix: launch_bounds(512,4) (VGPR cap 128); explicit 2-stage software pipeline
//   (prefetch next 4 rows while computing current 4); raw v_rcp_f32 for silu;
//   pointer-bump addressing; cache copy fused into the last t-block (its sliding
//   window already holds x[T-3..T-1] at loop exit) -> second kernel deleted.

#define B_   4
#define T_   4096
#define C_   2048
#define K_   4
#define C4_  (C_ / 4)   // 512 float4 groups per row
#define TT_  16         // timesteps per block

typedef float nat_float4 __attribute__((ext_vector_type(4)));

__device__ __forceinline__ float silu_f(float v) {
    // v * 1/(1+e^-v); raw v_rcp_f32 (approx, ~1ulp) instead of refined __frcp_rn.
    return v * __builtin_amdgcn_rcpf(1.f + __expf(-v));
}

__device__ __forceinline__ void store_nt(float4* p, const float4& v) {
    nat_float4 nv = { v.x, v.y, v.z, v.w };
    __builtin_nontemporal_store(nv, reinterpret_cast<nat_float4*>(p));
}

__global__ __launch_bounds__(C4_, 4) void dwconv_silu_kernel(
    const float4* __restrict__ x,      // [B, T, C4]
    const float4* __restrict__ kern,   // [K, C4]
    float4* __restrict__ y,            // [B, T, C4]
    float4* __restrict__ cache)        // [B, K-1, C4]
{
    const int c4 = threadIdx.x;        // 0..511
    const int b  = blockIdx.y;
    const int t0 = blockIdx.x * TT_;

    const float4 k0 = kern[0 * C4_ + c4];
    const float4 k1 = kern[1 * C4_ + c4];
    const float4 k2 = kern[2 * C4_ + c4];
    const float4 k3 = kern[3 * C4_ + c4];

    const float4* xr = x + ((size_t)b * T_ + t0) * C4_ + c4;
    float4*       yr = y + ((size_t)b * T_ + t0) * C4_ + c4;

    // Sliding window registers: xm1 = x[t-1], xm2 = x[t-2], xm3 = x[t-3]
    float4 xm1, xm2, xm3;
    if (t0 == 0) {
        xm1 = make_float4(0.f, 0.f, 0.f, 0.f);
        xm2 = xm1;
        xm3 = xm1;
    } else {
        xm1 = xr[-1 * C4_];
        xm2 = xr[-2 * C4_];
        xm3 = xr[-3 * C4_];
    }

    // Prologue of the 2-stage pipeline: first 4 rows in flight.
    float4 a0 = xr[0 * C4_];
    float4 a1 = xr[1 * C4_];
    float4 a2 = xr[2 * C4_];
    float4 a3 = xr[3 * C4_];
    xr += 4 * C4_;

#define CONV1(r, a, w1, w2, w3)                                              \
    r.x = fmaf(k0.x, a.x, fmaf(k1.x, w1.x, fmaf(k2.x, w2.x, k3.x * w3.x)));  \
    r.y = fmaf(k0.y, a.y, fmaf(k1.y, w1.y, fmaf(k2.y, w2.y, k3.y * w3.y)));  \
    r.z = fmaf(k0.z, a.z, fmaf(k1.z, w1.z, fmaf(k2.z, w2.z, k3.z * w3.z)));  \
    r.w = fmaf(k0.w, a.w, fmaf(k1.w, w1.w, fmaf(k2.w, w2.w, k3.w * w3.w)));  \
    r.x = silu_f(r.x); r.y = silu_f(r.y); r.z = silu_f(r.z); r.w = silu_f(r.w);

    #pragma unroll
    for (int i = 0; i < TT_; i += 4) {
        // Stage 1: issue the NEXT 4 loads before touching the current batch,
        // so 4 loads stay in flight under the compute+store of this batch.
        float4 n0, n1, n2, n3;
        if (i + 4 < TT_) {
            n0 = xr[0 * C4_];
            n1 = xr[1 * C4_];
            n2 = xr[2 * C4_];
            n3 = xr[3 * C4_];
            xr += 4 * C4_;
        }

        // Stage 2: compute + store the current batch.
        float4 r0, r1, r2, r3;
        CONV1(r0, a0, xm1, xm2, xm3)
        CONV1(r1, a1, a0,  xm1, xm2)
        CONV1(r2, a2, a1,  a0,  xm1)
        CONV1(r3, a3, a2,  a1,  a0)

        // y is write-once: non-temporal stores keep L2/LLC for x reuse.
        store_nt(&yr[0 * C4_], r0);
        store_nt(&yr[1 * C4_], r1);
        store_nt(&yr[2 * C4_], r2);
        store_nt(&yr[3 * C4_], r3);
        yr += 4 * C4_;

        xm3 = a1;
        xm2 = a2;
        xm1 = a3;

        if (i + 4 < TT_) {
            a0 = n0; a1 = n1; a2 = n2; a3 = n3;
        }
    }
#undef CONV1

    // Fused next_cache = x[:, T-3:, :]. The last t-block's window registers hold
    // exactly those rows at loop exit: xm3=x[T-3], xm2=x[T-2], xm1=x[T-1].
    if (t0 == T_ - TT_) {
        float4* cb = cache + (size_t)b * (K_ - 1) * C4_ + c4;
        cb[0 * C4_] = xm3;
        cb[1 * C4_] = xm2;
        cb[2 * C4_] = xm1;
    }
}

extern "C" void kernel_launch(void* const* d_in, const int* in_sizes, int n_in,
                              void* d_out, int out_size, void* d_ws, size_t ws_size,
                              hipStream_t stream)
{
    const float4* x    = (const float4*)d_in[0];
    const float4* kern = (const float4*)d_in[1];
    float*        out  = (float*)d_out;

    float4* y     = (float4*)out;
    float4* cache = (float4*)(out + (size_t)B_ * T_ * C_);

    dim3 grid(T_ / TT_, B_);   // (256, 4) = 1024 blocks
    dim3 block(C4_);           // 512 threads
    dwconv_silu_kernel<<<grid, block, 0, stream>>>(x, kern, y, cache);
}